// Round 9
// baseline (506.166 us; speedup 1.0000x reference)
//
#include <hip/hip_runtime.h>
#include <stdint.h>
#include <stddef.h>

typedef __attribute__((ext_vector_type(8))) _Float16 f16x8;
typedef __attribute__((ext_vector_type(4))) float f32x4;

#define D_IN 153
#define B_ROWS 262144
#define M_TILE 64
#define XB_STRIDE 168
#define G1H_STRIDE 68
#define H1_STRIDE 136
#define H2_STRIDE 72

// swizzled f16 weight layout offsets (in u16 elements, all multiples of 512)
#define OFF_WP 0
#define SZ_WP (5*10*512)
#define OFF_WG1 (OFF_WP + SZ_WP)
#define SZ_WG1 (5*4*512)
#define OFF_WE1 (OFF_WG1 + SZ_WG1)
#define SZ_WE1 (8*5*8*512)
#define OFF_WE2 (OFF_WE1 + SZ_WE1)
#define SZ_WE2 (8*4*4*512)
#define OFF_WE3 (OFF_WE2 + SZ_WE2)
#define SZ_WE3 (8*2*512)
#define OFF_WG2 (OFF_WE3 + SZ_WE3)
#define SZ_WG2 (2*2*512)
#define OFF_WG3 (OFF_WG2 + SZ_WG2)
#define SZ_WG3 (1*512)
#define TOTAL_W (OFF_WG3 + SZ_WG3)   // 275968 u16 = 551936 B

__device__ __forceinline__ unsigned short f2h(float f) {
    _Float16 h = (_Float16)f;                 // v_cvt_f16_f32, RNE
    union { _Float16 h; unsigned short u; } v; v.h = h;
    return v.u;
}
__device__ __forceinline__ float h2f(unsigned short u) {
    union { unsigned short u; _Float16 h; } v; v.u = u;
    return (float)v.h;
}

__device__ __forceinline__ f32x4 mfma16(f16x8 a, f16x8 b, f32x4 c) {
    return __builtin_amdgcn_mfma_f32_16x16x32_f16(a, b, c, 0, 0, 0);
}

// A-fragment from LDS: A[m = lane&15][k = quad*8 + j], 16B contiguous per lane
__device__ __forceinline__ f16x8 ldsA(const unsigned short* buf, int stride,
                                      int m0, int k0, int lane) {
    int row = m0 + (lane & 15);
    int col = k0 + (lane >> 4) * 8;
    return *(const f16x8*)(buf + row * stride + col);
}
// B-fragment from pre-swizzled global: tile of 64 lanes x 16B
__device__ __forceinline__ f16x8 ldB(const unsigned short* ws, int tile, int lane) {
    return *(const f16x8*)(ws + (size_t)tile * 512 + lane * 8);
}

// ---------------------------------------------------------------------------
// Weight conversion: fp32 -> fp16 in MFMA B-fragment-swizzled layout.
// (identical to R7/R8-passing version)
// ---------------------------------------------------------------------------
__global__ __launch_bounds__(256) void convert_weights(
        const float* __restrict__ Wp, const float* __restrict__ Wg1,
        const float* __restrict__ We1, const float* __restrict__ We2,
        const float* __restrict__ We3, const float* __restrict__ Wg2,
        const float* __restrict__ Wg3, unsigned short* __restrict__ ws) {
    int idx = blockIdx.x * 256 + threadIdx.x;
    if (idx >= TOTAL_W) return;
    int j = idx & 7;
    int lane = (idx >> 3) & 63;
    int t = idx >> 9;
    int quad = lane >> 4, nl = lane & 15;
    int kin = quad * 8 + j;
    float val = 0.f;
    if (idx < OFF_WG1) {                 // Wp [153][153], Kp=160 Np=160
        int kt = t / 10, nt = t % 10;
        int k = kt * 32 + kin, n = nt * 16 + nl;
        if (k < 153 && n < 153) val = Wp[k * 153 + n];
    } else if (idx < OFF_WE1) {          // Wg1 [153][64]
        int tt = t - (OFF_WG1 >> 9);
        int kt = tt / 4, nt = tt % 4;
        int k = kt * 32 + kin, n = nt * 16 + nl;
        if (k < 153) val = Wg1[k * 64 + n];
    } else if (idx < OFF_WE2) {          // We1 [8][153][128]
        int tt = t - (OFF_WE1 >> 9);
        int e = tt / 40, r = tt % 40, kt = r / 8, nt = r % 8;
        int k = kt * 32 + kin, n = nt * 16 + nl;
        if (k < 153) val = We1[((size_t)e * 153 + k) * 128 + n];
    } else if (idx < OFF_WE3) {          // We2 [8][128][64]
        int tt = t - (OFF_WE2 >> 9);
        int e = tt / 16, r = tt % 16, kt = r / 4, nt = r % 4;
        int k = kt * 32 + kin, n = nt * 16 + nl;
        val = We2[((size_t)e * 128 + k) * 64 + n];
    } else if (idx < OFF_WG2) {          // We3 [8][64][8], Np=16 (cols 8..15 zero)
        int tt = t - (OFF_WE3 >> 9);
        int e = tt / 2, kt = tt % 2;
        int k = kt * 32 + kin, n = nl;
        if (n < 8) val = We3[((size_t)e * 64 + k) * 8 + n];
    } else if (idx < OFF_WG3) {          // Wg2 [64][32]
        int tt = t - (OFF_WG2 >> 9);
        int kt = tt >> 1, nt = tt & 1;
        int k = kt * 32 + kin, n = nt * 16 + nl;
        val = Wg2[k * 32 + n];
    } else {                             // Wg3 [32][8] (cols 8..15 zero)
        int k = kin, n = nl;
        if (n < 8) val = Wg3[k * 8 + n];
    }
    ws[idx] = f2h(val);
}

// ---------------------------------------------------------------------------
// Fused MoE kernel: one block = 64 rows, 4 waves, 3 blocks/CU.
// ONLY change vs R8-passing kernel: expert loop is row-partitioned — wave w
// owns rows 16w..16w+15 for the full We1->We2->We3 chain. h1/h2 become
// wave-private slices of the same LDS regions; all intra-expert deps are
// same-wave LDS RAW (DS ops per-wave in-order) -> ZERO barriers in the loop
// (21 -> 5 barriers/block). ds_reads 36 -> 11 per expert. MFMA math and
// per-dot-product summation order bit-identical to R8.
// ---------------------------------------------------------------------------
__global__ __launch_bounds__(256, 2) void moe_main(
        const float* __restrict__ x,
        const float* __restrict__ ln_in_g, const float* __restrict__ ln_in_b,
        const float* __restrict__ bp,
        const float* __restrict__ bg1, const float* __restrict__ bg2,
        const float* __restrict__ bg3,
        const float* __restrict__ be1, const float* __restrict__ be2,
        const float* __restrict__ be3,
        const float* __restrict__ ln_out_g, const float* __restrict__ ln_out_b,
        const unsigned short* __restrict__ wsw,
        float* __restrict__ out) {
    const int tid = threadIdx.x;
    const int wave = tid >> 6, lane = tid & 63;
    const int quad = lane >> 4, nl = lane & 15;
    const size_t rowBase = (size_t)blockIdx.x * M_TILE;

    __shared__ __align__(16) char U[26624];  // xb -> g1h/g2s -> h1|h2
    __shared__ __align__(16) unsigned short xp[M_TILE * XB_STRIDE];  // x_proj f16
    __shared__ __align__(16) float gate[M_TILE * 8];
    unsigned short* xb  = (unsigned short*)U;              // [64][168] f16
    unsigned short* g1h = (unsigned short*)U;              // [64][68]  f16 (8704 B)
    unsigned short* g2s = (unsigned short*)(U + 17408);    // 4 x 512 u16 A-frags
    unsigned short* h1  = (unsigned short*)U;              // 4 x [16][136] f16 (wave-private)
    unsigned short* h2  = (unsigned short*)(U + 17408);    // 4 x [16][72]  f16 (wave-private)

    const f32x4 fzero = {0.f, 0.f, 0.f, 0.f};

    // ---- Phase 1: input LayerNorm (4 threads per row) ----
    {
        int r = tid >> 2, seg = tid & 3;
        const float* xr = x + (rowBase + r) * (size_t)D_IN;
        float vals[39];
        float s = 0.f, sq = 0.f;
        #pragma unroll
        for (int i = 0; i < 39; i++) {
            int c = seg + i * 4;
            float v = (c < D_IN) ? xr[c] : 0.f;
            vals[i] = v; s += v; sq += v * v;
        }
        s += __shfl_xor(s, 1);  s += __shfl_xor(s, 2);
        sq += __shfl_xor(sq, 1); sq += __shfl_xor(sq, 2);
        float mean = s * (1.f / 153.f);
        float var = sq * (1.f / 153.f) - mean * mean;
        float rstd = rsqrtf(var + 1e-5f);
        #pragma unroll
        for (int i = 0; i < 39; i++) {
            int c = seg + i * 4;
            if (c < D_IN) {
                float v = (vals[i] - mean) * rstd * ln_in_g[c] + ln_in_b[c];
                xb[r * XB_STRIDE + c] = f2h(v);
            }
        }
        if (tid < M_TILE) {
            #pragma unroll
            for (int c = D_IN; c < XB_STRIDE; c++) xb[tid * XB_STRIDE + c] = 0;
        }
    }
    __syncthreads();

    // ---- Phase 2: x_proj = relu(x_norm @ Wp + bp) + x_norm  (M=64,N=160,K=160)
    {
        f32x4 acc[3][4];
        #pragma unroll
        for (int q = 0; q < 3; q++)
            #pragma unroll
            for (int m = 0; m < 4; m++) acc[q][m] = fzero;
        const int nnt = (wave < 2) ? 3 : 2;
        for (int kt = 0; kt < 5; kt++) {
            f16x8 a0 = ldsA(xb, XB_STRIDE, 0,  kt * 32, lane);
            f16x8 a1 = ldsA(xb, XB_STRIDE, 16, kt * 32, lane);
            f16x8 a2 = ldsA(xb, XB_STRIDE, 32, kt * 32, lane);
            f16x8 a3 = ldsA(xb, XB_STRIDE, 48, kt * 32, lane);
            #pragma unroll
            for (int q = 0; q < 3; q++) {
                if (q < nnt) {
                    int nt = wave + 4 * q;
                    f16x8 b = ldB(wsw, (OFF_WP >> 9) + kt * 10 + nt, lane);
                    acc[q][0] = mfma16(a0, b, acc[q][0]);
                    acc[q][1] = mfma16(a1, b, acc[q][1]);
                    acc[q][2] = mfma16(a2, b, acc[q][2]);
                    acc[q][3] = mfma16(a3, b, acc[q][3]);
                }
            }
        }
        #pragma unroll
        for (int q = 0; q < 3; q++) {
            if (q < nnt) {
                int nt = wave + 4 * q;
                int col = nt * 16 + nl;
                float bpv = (col < D_IN) ? bp[col] : 0.f;
                #pragma unroll
                for (int m = 0; m < 4; m++)
                    #pragma unroll
                    for (int i = 0; i < 4; i++) {
                        int row = m * 16 + quad * 4 + i;
                        float v = fmaxf(acc[q][m][i] + bpv, 0.f)
                                  + h2f(xb[row * XB_STRIDE + col]);
                        xp[row * XB_STRIDE + col] = f2h(v);
                    }
            }
        }
        if (tid < M_TILE) {
            #pragma unroll
            for (int c = 160; c < XB_STRIDE; c++) xp[tid * XB_STRIDE + c] = 0;
        }
    }
    __syncthreads();  // B2: xp ready; xb dead -> U reusable as g1h

    // ---- Phase 3: g1 = relu(x_proj @ Wg1 + bg1) -> f16 row-major (M=64,N=64,K=160)
    {
        f32x4 acc[4];
        #pragma unroll
        for (int m = 0; m < 4; m++) acc[m] = fzero;
        for (int kt = 0; kt < 5; kt++) {
            f16x8 a0 = ldsA(xp, XB_STRIDE, 0,  kt * 32, lane);
            f16x8 a1 = ldsA(xp, XB_STRIDE, 16, kt * 32, lane);
            f16x8 a2 = ldsA(xp, XB_STRIDE, 32, kt * 32, lane);
            f16x8 a3 = ldsA(xp, XB_STRIDE, 48, kt * 32, lane);
            f16x8 b = ldB(wsw, (OFF_WG1 >> 9) + kt * 4 + wave, lane);
            acc[0] = mfma16(a0, b, acc[0]);
            acc[1] = mfma16(a1, b, acc[1]);
            acc[2] = mfma16(a2, b, acc[2]);
            acc[3] = mfma16(a3, b, acc[3]);
        }
        int col = wave * 16 + nl;
        float bv = bg1[col];
        #pragma unroll
        for (int m = 0; m < 4; m++)
            #pragma unroll
            for (int i = 0; i < 4; i++) {
                int row = m * 16 + quad * 4 + i;
                g1h[row * G1H_STRIDE + col] = f2h(fmaxf(acc[m][i] + bv, 0.f));
            }
    }
    __syncthreads();  // B3: g1h ready

    // ---- Phase 4: g2 = relu(g1 @ Wg2 + bg2) via MFMA (per-wave 16 rows; M=16,N=32,K=64)
    {
        f16x8 a0 = ldsA(g1h, G1H_STRIDE, wave * 16, 0,  lane);
        f16x8 a1 = ldsA(g1h, G1H_STRIDE, wave * 16, 32, lane);
        f32x4 accg[2] = {fzero, fzero};
        #pragma unroll
        for (int nt = 0; nt < 2; nt++) {
            accg[nt] = mfma16(a0, ldB(wsw, (OFF_WG2 >> 9) + 0 * 2 + nt, lane), accg[nt]);
            accg[nt] = mfma16(a1, ldB(wsw, (OFF_WG2 >> 9) + 1 * 2 + nt, lane), accg[nt]);
        }
        // repack C (col=nl+16*nt, row=quad*4+i) -> wave-private 16x32 A-frag
        unsigned short* g2w = g2s + wave * 512;
        #pragma unroll
        for (int nt = 0; nt < 2; nt++) {
            float bv = bg2[nt * 16 + nl];
            #pragma unroll
            for (int i = 0; i < 4; i++) {
                int col = nt * 16 + nl;
                int row = quad * 4 + i;
                int off = (col >> 3) * 128 + row * 8 + (col & 7);
                g2w[off] = f2h(fmaxf(accg[nt][i] + bv, 0.f));
            }
        }
    }
    __syncthreads();  // B4a: g2s ready

    // ---- Phase 5: logits = g2 @ Wg3 + bg3 via MFMA + softmax (per-wave 16 rows)
    {
        f16x8 ag2 = *(const f16x8*)(g2s + wave * 512 + lane * 8);
        f32x4 lg = mfma16(ag2, ldB(wsw, (OFF_WG3 >> 9), lane), fzero);
        float bg3v = (nl < 8) ? bg3[nl] : 0.f;
        #pragma unroll
        for (int i = 0; i < 4; i++) {
            float v = lg[i] + bg3v;
            float m = v;
            m = fmaxf(m, __shfl_xor(m, 1));
            m = fmaxf(m, __shfl_xor(m, 2));
            m = fmaxf(m, __shfl_xor(m, 4));
            float e = __expf(v - m);
            float ssum = e + __shfl_xor(e, 1);
            ssum += __shfl_xor(ssum, 2);
            ssum += __shfl_xor(ssum, 4);
            float g = e / ssum;
            if (nl < 8) {
                int row = wave * 16 + quad * 4 + i;
                gate[row * 8 + nl] = g;
                out[(size_t)B_ROWS * 8 + (rowBase + row) * 8 + nl] = g;
            }
        }
    }
    __syncthreads();  // B4: gate ready; U region free for h1/h2 (last block barrier)

    // ---- Phase 6: experts, row-partitioned: wave w owns rows 16w..16w+15 ----
    // All h1/h2 traffic is wave-private (same-wave DS ops are in-order);
    // xp/gate are read-only here. NO barriers in this loop.
    float oacc[4] = {0.f, 0.f, 0.f, 0.f};
    {
        unsigned short* h1w = h1 + wave * 16 * H1_STRIDE;   // [16][136]
        unsigned short* h2w = h2 + wave * 16 * H2_STRIDE;   // [16][72]
        for (int e = 0; e < 8; e++) {
            // We1: h1w = relu(xp[rows] @ We1[e] + be1[e])  (M=16,N=128,K=160)
            {
                f32x4 acc1[8];
                #pragma unroll
                for (int nt = 0; nt < 8; nt++) acc1[nt] = fzero;
                for (int kt = 0; kt < 5; kt++) {
                    f16x8 a = ldsA(xp, XB_STRIDE, wave * 16, kt * 32, lane);
                    int tb = (OFF_WE1 >> 9) + (e * 5 + kt) * 8;
                    #pragma unroll
                    for (int nt = 0; nt < 8; nt++)
                        acc1[nt] = mfma16(a, ldB(wsw, tb + nt, lane), acc1[nt]);
                }
                #pragma unroll
                for (int nt = 0; nt < 8; nt++) {
                    int col = nt * 16 + nl;
                    float bv = be1[e * 128 + col];
                    #pragma unroll
                    for (int i = 0; i < 4; i++)
                        h1w[(quad * 4 + i) * H1_STRIDE + col] =
                            f2h(fmaxf(acc1[nt][i] + bv, 0.f));
                }
            }
            // We2: h2w = relu(h1w @ We2[e] + be2[e])  (M=16,N=64,K=128)
            {
                f32x4 acc2[4];
                #pragma unroll
                for (int nt = 0; nt < 4; nt++) acc2[nt] = fzero;
                for (int kt = 0; kt < 4; kt++) {
                    f16x8 a = ldsA(h1w, H1_STRIDE, 0, kt * 32, lane);
                    int tb = (OFF_WE2 >> 9) + (e * 4 + kt) * 4;
                    #pragma unroll
                    for (int nt = 0; nt < 4; nt++)
                        acc2[nt] = mfma16(a, ldB(wsw, tb + nt, lane), acc2[nt]);
                }
                #pragma unroll
                for (int nt = 0; nt < 4; nt++) {
                    int col = nt * 16 + nl;
                    float bv = be2[e * 64 + col];
                    #pragma unroll
                    for (int i = 0; i < 4; i++)
                        h2w[(quad * 4 + i) * H2_STRIDE + col] =
                            f2h(fmaxf(acc2[nt][i] + bv, 0.f));
                }
            }
            // We3 + gated accumulate  (M=16,N=16(8),K=64)
            {
                f32x4 acc3 = fzero;
                #pragma unroll
                for (int kt = 0; kt < 2; kt++) {
                    f16x8 a = ldsA(h2w, H2_STRIDE, 0, kt * 32, lane);
                    f16x8 b = ldB(wsw, (OFF_WE3 >> 9) + e * 2 + kt, lane);
                    acc3 = mfma16(a, b, acc3);
                }
                if (nl < 8) {
                    float bv = be3[e * 8 + nl];
                    #pragma unroll
                    for (int i = 0; i < 4; i++) {
                        int row = wave * 16 + quad * 4 + i;
                        oacc[i] += gate[row * 8 + e] * (acc3[i] + bv);
                    }
                }
            }
        }
    }

    // ---- Phase 7: output LayerNorm over 8 + store ----
    {
        float go = 1.f, bo = 0.f;
        if (nl < 8) { go = ln_out_g[nl]; bo = ln_out_b[nl]; }
        #pragma unroll
        for (int i = 0; i < 4; i++) {
            float v = oacc[i];
            float s = v + __shfl_xor(v, 1);
            s += __shfl_xor(s, 2);
            s += __shfl_xor(s, 4);
            float q2 = v * v;
            float q = q2 + __shfl_xor(q2, 1);
            q += __shfl_xor(q, 2);
            q += __shfl_xor(q, 4);
            float mean = s * 0.125f;
            float var = q * 0.125f - mean * mean;
            float rstd = rsqrtf(var + 1e-5f);
            float ov = (v - mean) * rstd * go + bo;
            if (nl < 8) {
                size_t row = rowBase + wave * 16 + quad * 4 + i;
                out[row * 8 + nl] = ov;
            }
        }
    }
}

extern "C" void kernel_launch(void* const* d_in, const int* in_sizes, int n_in,
                              void* d_out, int out_size, void* d_ws, size_t ws_size,
                              hipStream_t stream) {
    const float* x        = (const float*)d_in[0];
    const float* ln_in_g  = (const float*)d_in[1];
    const float* ln_in_b  = (const float*)d_in[2];
    const float* Wp       = (const float*)d_in[3];
    const float* bp       = (const float*)d_in[4];
    const float* Wg1      = (const float*)d_in[5];
    const float* bg1      = (const float*)d_in[6];
    const float* Wg2      = (const float*)d_in[7];
    const float* bg2      = (const float*)d_in[8];
    const float* Wg3      = (const float*)d_in[9];
    const float* bg3      = (const float*)d_in[10];
    const float* We1      = (const float*)d_in[11];
    const float* be1      = (const float*)d_in[12];
    const float* We2      = (const float*)d_in[13];
    const float* be2      = (const float*)d_in[14];
    const float* We3      = (const float*)d_in[15];
    const float* be3      = (const float*)d_in[16];
    const float* ln_out_g = (const float*)d_in[17];
    const float* ln_out_b = (const float*)d_in[18];
    unsigned short* ws = (unsigned short*)d_ws;
    float* out = (float*)d_out;

    convert_weights<<<(TOTAL_W + 255) / 256, 256, 0, stream>>>(
        Wp, Wg1, We1, We2, We3, Wg2, Wg3, ws);
    moe_main<<<B_ROWS / M_TILE, 256, 0, stream>>>(
        x, ln_in_g, ln_in_b, bp, bg1, bg2, bg3,
        be1, be2, be3, ln_out_g, ln_out_b, ws, out);
}